// Round 12
// baseline (208.183 us; speedup 1.0000x reference)
//
#include <hip/hip_runtime.h>
#include <math.h>
#include <stdint.h>

#define HW    112
#define HW2   (112 * 112)
#define NIMG  64
#define CIN   128
#define NKG   4            // split-K groups over input channels
#define ICG   (CIN / NKG)  // 32 ic per group
#define NPAIR (ICG / 2)    // 16 channel-pairs per group
#define TILEP 2016         // LDS slot stride in floats (16B multiple, exact tile)

__device__ __forceinline__ float gelu_exact(float v) {
    return 0.5f * v * (1.0f + erff(v * 0.70710678118654752f));
}

// ---------------------------------------------------------------------------
// K1a: partial[kg][n][oc][h][w] = sum over 32-ch group of conv3x3(x, w1)
// grid (7, 64, 4) = 1792 blocks, block 256. Double-buffered LDS staging with
// TWO channels per buffer (CPB=2): 16 barrier-iterations instead of 32,
// 252 FMA/thread per iteration (~1000 cy) >= HBM latency, 4 loads in
// flight/wave. LDS 32.3 KB -> 4 resident blocks/CU (16 waves).
// ---------------------------------------------------------------------------
__global__ __launch_bounds__(256) void k1_partial(
    const float* __restrict__ x, const float* __restrict__ w1,
    float* __restrict__ part) {
    __shared__ __align__(16) float tile[2][2][TILEP];  // [buf][ch-of-pair][px]

    const int tid = threadIdx.x;
    const int bx  = blockIdx.x;   // 0..6 h-tiles
    const int n   = blockIdx.y;
    const int kg  = blockIdx.z;
    const int h0  = bx * 16;
    const int icb = kg * ICG;

    const int tx   = tid & 15;
    const int ty   = tid >> 4;
    const int col0 = tx * 7;

    // zero border rows once (never overwritten by staging)
    if (bx == 0 && tid < HW) {
        tile[0][0][tid] = 0.f; tile[0][1][tid] = 0.f;
        tile[1][0][tid] = 0.f; tile[1][1][tid] = 0.f;
    }
    if (bx == 6 && tid < HW) {
        tile[0][0][17 * HW + tid] = 0.f; tile[0][1][17 * HW + tid] = 0.f;
        tile[1][0][17 * HW + tid] = 0.f; tile[1][1][17 * HW + tid] = 0.f;
    }

    const int    ldsoff = (bx == 0) ? HW : 0;                 // skip zero row 0
    const int    count4 = (bx == 0 || bx == 6) ? 476 : 504;   // float4s staged
    const size_t srcoff = (bx == 0) ? 0 : (size_t)(h0 - 1) * HW;
    const float* xn = x + ((size_t)n * CIN + icb) * HW2 + srcoff;

    const float lmask = (col0 > 0) ? 1.f : 0.f;
    const float rmask = (col0 + 7 < HW) ? 1.f : 0.f;
    const int   loff  = (col0 > 0) ? -1 : 0;
    const int   roff  = (col0 + 7 < HW) ? 7 : 0;

    float acc0[7] = {0.f, 0.f, 0.f, 0.f, 0.f, 0.f, 0.f};
    float acc1[7] = {0.f, 0.f, 0.f, 0.f, 0.f, 0.f, 0.f};

    // stage channel pair P (channels 2P, 2P+1) into buffer BUF
#define STAGE2(P, BUF)                                                         \
    do {                                                                       \
        _Pragma("unroll")                                                      \
        for (int _s = 0; _s < 2; ++_s) {                                       \
            const float* _src = xn + (size_t)(2 * (P) + _s) * HW2;             \
            float* _dst = &tile[(BUF)][_s][ldsoff];                            \
            _Pragma("unroll")                                                  \
            for (int _r = 0; _r < 2; ++_r) {                                   \
                const int _i = tid + _r * 256;                                 \
                if (_i < count4)                                               \
                    __builtin_amdgcn_global_load_lds(                          \
                        (const __attribute__((address_space(1))) unsigned int*)(_src + (size_t)_i * 4), \
                        (__attribute__((address_space(3))) unsigned int*)(_dst + _i * 4), \
                        16, 0, 0);                                             \
            }                                                                  \
        }                                                                      \
    } while (0)

    // prologue: stage pair 0 into buf 0
    STAGE2(0, 0);
    __syncthreads();   // buf0 ready for all waves

    int buf = 0;
    for (int p = 0; p < NPAIR; ++p) {
        // issue async prefetch of pair p+1 into other buffer (flies during compute)
        if (p + 1 < NPAIR) STAGE2(p + 1, buf ^ 1);

        // compute both channels of pair p from LDS
#pragma unroll
        for (int s = 0; s < 2; ++s) {
            const int ic = 2 * p + s;
            const float* wa = w1 + (size_t)(icb + ic) * 9;   // oc = 0
            const float* wb = wa + (size_t)CIN * 9;          // oc = 1
            const float* tl = tile[buf][s];
#pragma unroll
            for (int dr = 0; dr < 3; ++dr) {
                const int base = (ty + dr) * HW + col0;
                float v[9];
                v[0] = tl[base + loff] * lmask;
#pragma unroll
                for (int k = 1; k <= 7; ++k) v[k] = tl[base + (k - 1)];
                v[8] = tl[base + roff] * rmask;
                const float a0 = wa[dr * 3 + 0], a1 = wa[dr * 3 + 1], a2 = wa[dr * 3 + 2];
                const float c0 = wb[dr * 3 + 0], c1 = wb[dr * 3 + 1], c2 = wb[dr * 3 + 2];
#pragma unroll
                for (int j = 0; j < 7; ++j) {
                    acc0[j] += a0 * v[j] + a1 * v[j + 1] + a2 * v[j + 2];
                    acc1[j] += c0 * v[j] + c1 * v[j + 1] + c2 * v[j + 2];
                }
            }
        }

        __syncthreads();   // prefetch landed; all waves done reading buf
        buf ^= 1;
    }
#undef STAGE2

    const size_t obase = ((size_t)kg * NIMG + n) * 2;
    float* p0 = part + (obase + 0) * HW2 + (size_t)(h0 + ty) * HW + col0;
    float* p1 = part + (obase + 1) * HW2 + (size_t)(h0 + ty) * HW + col0;
#pragma unroll
    for (int j = 0; j < 7; ++j) { p0[j] = acc0[j]; p1[j] = acc1[j]; }
}

// ---------------------------------------------------------------------------
// K2f: fused reduce(4 partials)+bias+GELU staging -> conv2 -> sigmoid -> s0.
// grid (7, 64), block 448. g is never materialized in HBM.
// ---------------------------------------------------------------------------
__global__ __launch_bounds__(448) void k2f_reduce_conv2(
    const float* __restrict__ part, const float* __restrict__ b1,
    const float* __restrict__ w2, const float* __restrict__ b2,
    float* __restrict__ s0) {
    __shared__ __align__(16) float gs[2][18 * HW];  // tile row r <-> global h0-1+r

    const int tid = threadIdx.x;
    const int bx  = blockIdx.x;
    const int n   = blockIdx.y;
    const int h0  = bx * 16;
    const size_t kstride = (size_t)NIMG * 2 * HW2;

    // stage g-tile: sum 4 partials + bias, gelu; zero rows outside image
    for (int i = tid; i < 1008; i += 448) {
        const int ch  = i / 504;
        const int rem = i - ch * 504;
        const int r   = rem / 28;
        const int c4  = rem - r * 28;
        const int hh  = h0 - 1 + r;
        float4 v = make_float4(0.f, 0.f, 0.f, 0.f);
        if (hh >= 0 && hh < HW) {
            const float* p = part + ((size_t)n * 2 + ch) * HW2 + (size_t)hh * HW + c4 * 4;
            float4 a = *reinterpret_cast<const float4*>(p);
#pragma unroll
            for (int kg = 1; kg < NKG; ++kg) {
                const float4 q = *reinterpret_cast<const float4*>(p + kg * kstride);
                a.x += q.x; a.y += q.y; a.z += q.z; a.w += q.w;
            }
            const float bb = b1[ch];
            v.x = gelu_exact(a.x + bb);
            v.y = gelu_exact(a.y + bb);
            v.z = gelu_exact(a.z + bb);
            v.w = gelu_exact(a.w + bb);
        }
        *reinterpret_cast<float4*>(&gs[ch][r * HW + c4 * 4]) = v;
    }
    __syncthreads();

    // conv2 + sigmoid for this thread's 4 px
    const int row  = tid / 28;          // 0..15
    const int col0 = (tid - row * 28) * 4;
    const float lm = (col0 > 0) ? 1.f : 0.f;
    const float rm = (col0 + 4 < HW) ? 1.f : 0.f;
    const int   lo = (col0 > 0) ? -1 : 0;
    const int   ro = (col0 + 4 < HW) ? 1 : 0;   // right halo = gs[base+4]

    float accA[4], accB[4];
    const float bb0 = b2[0], bb1 = b2[1];
#pragma unroll
    for (int j = 0; j < 4; ++j) { accA[j] = bb0; accB[j] = bb1; }

#pragma unroll
    for (int ch = 0; ch < 2; ++ch) {
        const float* wa = w2 + ch * 9;        // oc = 0
        const float* wb = w2 + (2 + ch) * 9;  // oc = 1
#pragma unroll
        for (int dr = 0; dr < 3; ++dr) {
            const int base = (row + dr) * HW + col0;
            const float4 c4 = *reinterpret_cast<const float4*>(&gs[ch][base]);
            const float v0 = gs[ch][base + lo] * lm;
            const float v5 = gs[ch][base + 3 + ro] * rm;
            const float v1 = c4.x, v2 = c4.y, v3 = c4.z, v4 = c4.w;
            const float a0 = wa[dr * 3], a1 = wa[dr * 3 + 1], a2 = wa[dr * 3 + 2];
            const float c0 = wb[dr * 3], c1 = wb[dr * 3 + 1], c2 = wb[dr * 3 + 2];
            accA[0] += a0 * v0 + a1 * v1 + a2 * v2;
            accA[1] += a0 * v1 + a1 * v2 + a2 * v3;
            accA[2] += a0 * v2 + a1 * v3 + a2 * v4;
            accA[3] += a0 * v3 + a1 * v4 + a2 * v5;
            accB[0] += c0 * v0 + c1 * v1 + c2 * v2;
            accB[1] += c0 * v1 + c1 * v2 + c2 * v3;
            accB[2] += c0 * v2 + c1 * v3 + c2 * v4;
            accB[3] += c0 * v3 + c1 * v4 + c2 * v5;
        }
    }

    float4 o;
    o.x = 1.0f / (1.0f + expf(gelu_exact(accB[0]) - gelu_exact(accA[0])));
    o.y = 1.0f / (1.0f + expf(gelu_exact(accB[1]) - gelu_exact(accA[1])));
    o.z = 1.0f / (1.0f + expf(gelu_exact(accB[2]) - gelu_exact(accA[2])));
    o.w = 1.0f / (1.0f + expf(gelu_exact(accB[3]) - gelu_exact(accA[3])));
    *reinterpret_cast<float4*>(s0 + (size_t)n * HW2 + (size_t)(h0 + row) * HW + col0) = o;
}

// ---------------------------------------------------------------------------
// Fallback path (only if ws too small): monolithic k1 -> g, then k2 -> s0
// ---------------------------------------------------------------------------
__global__ __launch_bounds__(448) void k1_conv1_gelu(
    const float* __restrict__ x, const float* __restrict__ w1,
    const float* __restrict__ b1, float* __restrict__ g) {
    const int n  = blockIdx.y;
    const int h  = blockIdx.x * 16 + threadIdx.y;
    const int w0 = threadIdx.x * 4;
    float acc0[4], acc1[4];
    const float bb0 = b1[0], bb1 = b1[1];
#pragma unroll
    for (int j = 0; j < 4; ++j) { acc0[j] = bb0; acc1[j] = bb1; }
    const float* xn = x + (size_t)n * CIN * HW2;
#pragma unroll 4
    for (int ic = 0; ic < CIN; ++ic) {
        const float* xc = xn + (size_t)ic * HW2;
        const float* wa = w1 + ic * 9;
        const float* wb = w1 + (CIN + ic) * 9;
#pragma unroll
        for (int dh = -1; dh <= 1; ++dh) {
            const int hh = h + dh;
            if (hh < 0 || hh >= HW) continue;
            const float* xr = xc + hh * HW;
            const float4 c4  = *reinterpret_cast<const float4*>(xr + w0);
            const float left  = (w0 > 0)      ? xr[w0 - 1] : 0.0f;
            const float right = (w0 + 4 < HW) ? xr[w0 + 4] : 0.0f;
            const float v0 = left, v1 = c4.x, v2 = c4.y, v3 = c4.z, v4 = c4.w, v5 = right;
            const int r = (dh + 1) * 3;
            const float a0 = wa[r], a1 = wa[r + 1], a2 = wa[r + 2];
            const float c0 = wb[r], c1 = wb[r + 1], c2 = wb[r + 2];
            acc0[0] += a0 * v0 + a1 * v1 + a2 * v2;
            acc0[1] += a0 * v1 + a1 * v2 + a2 * v3;
            acc0[2] += a0 * v2 + a1 * v3 + a2 * v4;
            acc0[3] += a0 * v3 + a1 * v4 + a2 * v5;
            acc1[0] += c0 * v0 + c1 * v1 + c2 * v2;
            acc1[1] += c0 * v1 + c1 * v2 + c2 * v3;
            acc1[2] += c0 * v2 + c1 * v3 + c2 * v4;
            acc1[3] += c0 * v3 + c1 * v4 + c2 * v5;
        }
    }
    float4 o0, o1;
    o0.x = gelu_exact(acc0[0]); o0.y = gelu_exact(acc0[1]);
    o0.z = gelu_exact(acc0[2]); o0.w = gelu_exact(acc0[3]);
    o1.x = gelu_exact(acc1[0]); o1.y = gelu_exact(acc1[1]);
    o1.z = gelu_exact(acc1[2]); o1.w = gelu_exact(acc1[3]);
    float* g0 = g + (size_t)(n * 2 + 0) * HW2 + h * HW + w0;
    float* g1 = g + (size_t)(n * 2 + 1) * HW2 + h * HW + w0;
    *reinterpret_cast<float4*>(g0) = o0;
    *reinterpret_cast<float4*>(g1) = o1;
}

__global__ __launch_bounds__(448) void k2_conv2_softmax(
    const float* __restrict__ g, const float* __restrict__ w2,
    const float* __restrict__ b2, float* __restrict__ s0) {
    const int n  = blockIdx.y;
    const int h  = blockIdx.x * 16 + threadIdx.y;
    const int w0 = threadIdx.x * 4;
    float accA[4], accB[4];
    const float bb0 = b2[0], bb1 = b2[1];
#pragma unroll
    for (int j = 0; j < 4; ++j) { accA[j] = bb0; accB[j] = bb1; }
#pragma unroll
    for (int c = 0; c < 2; ++c) {
        const float* gc = g + (size_t)(n * 2 + c) * HW2;
        const float* wa = w2 + c * 9;
        const float* wb = w2 + (2 + c) * 9;
#pragma unroll
        for (int dh = -1; dh <= 1; ++dh) {
            const int hh = h + dh;
            if (hh < 0 || hh >= HW) continue;
            const float* gr = gc + hh * HW;
            const float4 c4  = *reinterpret_cast<const float4*>(gr + w0);
            const float left  = (w0 > 0)      ? gr[w0 - 1] : 0.0f;
            const float right = (w0 + 4 < HW) ? gr[w0 + 4] : 0.0f;
            const float v0 = left, v1 = c4.x, v2 = c4.y, v3 = c4.z, v4 = c4.w, v5 = right;
            const int r = (dh + 1) * 3;
            const float a0 = wa[r], a1 = wa[r + 1], a2 = wa[r + 2];
            const float c0 = wb[r], c1 = wb[r + 1], c2 = wb[r + 2];
            accA[0] += a0 * v0 + a1 * v1 + a2 * v2;
            accA[1] += a0 * v1 + a1 * v2 + a2 * v3;
            accA[2] += a0 * v2 + a1 * v3 + a2 * v4;
            accA[3] += a0 * v3 + a1 * v4 + a2 * v5;
            accB[0] += c0 * v0 + c1 * v1 + c2 * v2;
            accB[1] += c0 * v1 + c1 * v2 + c2 * v3;
            accB[2] += c0 * v2 + c1 * v3 + c2 * v4;
            accB[3] += c0 * v3 + c1 * v4 + c2 * v5;
        }
    }
    float4 o;
    o.x = 1.0f / (1.0f + expf(gelu_exact(accB[0]) - gelu_exact(accA[0])));
    o.y = 1.0f / (1.0f + expf(gelu_exact(accB[1]) - gelu_exact(accA[1])));
    o.z = 1.0f / (1.0f + expf(gelu_exact(accB[2]) - gelu_exact(accA[2])));
    o.w = 1.0f / (1.0f + expf(gelu_exact(accB[3]) - gelu_exact(accA[3])));
    *reinterpret_cast<float4*>(s0 + (size_t)n * HW2 + h * HW + w0) = o;
}

// K3: out[b][c][t][h][w] = s0*x1 + (1-s0)*x2 — flat balanced grid (roofline)
__global__ __launch_bounds__(256) void k3_blend(
    const float* __restrict__ x, const float* __restrict__ s0,
    float* __restrict__ out, int total4) {
    int idx = blockIdx.x * blockDim.x + threadIdx.x;
    if (idx >= total4) return;
    const int W4 = HW / 4;
    int w4  = idx % W4;
    int tmp = idx / W4;
    int h   = tmp % HW; tmp /= HW;
    int t   = tmp % 16; tmp /= 16;
    int c   = tmp % 64;
    int b   = tmp / 64;
    const int n = b * 16 + t;

    const size_t px = (size_t)h * HW + w4 * 4;
    const float4 x1 = *reinterpret_cast<const float4*>(x + (size_t)(n * CIN + c)      * HW2 + px);
    const float4 x2 = *reinterpret_cast<const float4*>(x + (size_t)(n * CIN + c + 64) * HW2 + px);
    const float4 s  = *reinterpret_cast<const float4*>(s0 + (size_t)n * HW2 + px);

    float4 o;
    o.x = s.x * x1.x + (1.0f - s.x) * x2.x;
    o.y = s.y * x1.y + (1.0f - s.y) * x2.y;
    o.z = s.z * x1.z + (1.0f - s.z) * x2.z;
    o.w = s.w * x1.w + (1.0f - s.w) * x2.w;
    *reinterpret_cast<float4*>(out + (size_t)idx * 4) = o;
}

extern "C" void kernel_launch(void* const* d_in, const int* in_sizes, int n_in,
                              void* d_out, int out_size, void* d_ws, size_t ws_size,
                              hipStream_t stream) {
    const float* x  = (const float*)d_in[0];
    const float* w1 = (const float*)d_in[1];
    const float* b1 = (const float*)d_in[2];
    const float* w2 = (const float*)d_in[3];
    const float* b2 = (const float*)d_in[4];
    float* out = (float*)d_out;

    const size_t partF = (size_t)NKG * NIMG * 2 * HW2;  // 25.7 MB
    const size_t gF    = (size_t)NIMG * 2 * HW2;        //  6.4 MB
    const size_t s0F   = (size_t)NIMG * HW2;            //  3.2 MB
    const size_t need  = (partF + s0F) * sizeof(float);

    dim3 grd(7, NIMG);
    float* s0;

    if (ws_size >= need) {
        float* part = (float*)d_ws;
        s0 = part + partF;
        dim3 grdp(7, NIMG, NKG);
        k1_partial<<<grdp, 256, 0, stream>>>(x, w1, part);
        k2f_reduce_conv2<<<grd, 448, 0, stream>>>(part, b1, w2, b2, s0);
    } else {
        float* g = (float*)d_ws;
        s0 = g + gF;
        dim3 blk(28, 16);
        k1_conv1_gelu<<<grd, blk, 0, stream>>>(x, w1, b1, g);
        k2_conv2_softmax<<<grd, blk, 0, stream>>>(g, w2, b2, s0);
    }

    const int total4 = 4 * 64 * 16 * HW * (HW / 4);
    k3_blend<<<(total4 + 255) / 256, 256, 0, stream>>>(x, s0, out, total4);
}